// Round 4
// baseline (113.403 us; speedup 1.0000x reference)
//
#include <hip/hip_runtime.h>

#define NEG_BIG (-3.0e38f)

// One block = 256 threads = 4 waves; each wave handles 2 samples (one per
// 32-lane half). Lane m owns TWO 4-lag groups: sh = 4m+q and sh = 128+4m+q
// (q=0..3; sh=255 is a dummy). Each group's sliding window moves at lane
// stride -1 slot (conflict-free linear LDS, compile-time chunk offsets).
// Per-half LDS (544 floats):
//   apad floats [0,392): zeros[0,128) | raw audio [128,256) | zeros [256,392)
//   video floats [392,520)  (broadcast-read per chunk)
// corr_raw[sh] = sum_j v[j]*apad[j - sh + 255]; window slot for group g:
//   S_g(c) = c + 63 - 32*g - m; w[t] = apad[4*S + t]; acc_gq += v[4c+e]*w[3+e-q].
__global__ __launch_bounds__(256, 8) void avsync_kernel(
    const float* __restrict__ video, const float* __restrict__ audio,
    const float* __restrict__ W1, const float* __restrict__ b1,
    const float* __restrict__ W2, const float* __restrict__ b2,
    float* __restrict__ out) {
  __shared__ float lds[4][2][544];

  const int tid  = threadIdx.x;
  const int wid  = tid >> 6;
  const int lane = tid & 63;
  const int half = lane >> 5;
  const int m    = lane & 31;
  const int b    = (int)blockIdx.x * 8 + wid * 2 + half;

  float* hbase = &lds[wid][half][0];

  const float4 v4 = *reinterpret_cast<const float4*>(video + (size_t)b * 128 + 4 * m);
  const float4 a4 = *reinterpret_cast<const float4*>(audio + (size_t)b * 128 + 4 * m);

  // ---- stage raw data (wave-private region, no barrier needed) ----
  float4 z4; z4.x = z4.y = z4.z = z4.w = 0.0f;
  float4* sl = reinterpret_cast<float4*>(hbase);
  sl[m]      = z4;        // apad slots [0,32)   = zeros
  sl[64 + m] = z4;        // apad slots [64,96)  = zeros
  if (m < 2) sl[96 + m] = z4;   // slots 96,97 zeros
  sl[32 + m] = a4;        // apad slots [32,64)  = raw audio
  *reinterpret_cast<float4*>(hbase + 392 + 4 * m) = v4;   // video

  // ---- norms (per half) ----
  float pv = v4.x * v4.x + v4.y * v4.y + v4.z * v4.z + v4.w * v4.w;
  float pa = a4.x * a4.x + a4.y * a4.y + a4.z * a4.z + a4.w * a4.w;
#pragma unroll
  for (int off = 1; off < 32; off <<= 1) {
    pv += __shfl_xor(pv, off, 32);
    pa += __shfl_xor(pa, off, 32);
  }
  const float nv = sqrtf(pv);
  const float na = sqrtf(pa);
  const float iv = 1.0f / fmaxf(nv, 1e-12f);
  const float ia = 1.0f / fmaxf(na, 1e-12f);

  // ---- phase statistic on normalized difference ----
  const float d0 = v4.x * iv - a4.x * ia;
  const float d1 = v4.y * iv - a4.y * ia;
  const float d2 = v4.z * iv - a4.z * ia;
  const float d3 = v4.w * iv - a4.w * ia;
  float sc = __cosf(d0) + __cosf(d1) + __cosf(d2) + __cosf(d3);
  float ss = __sinf(d0) + __sinf(d1) + __sinf(d2) + __sinf(d3);
#pragma unroll
  for (int off = 1; off < 32; off <<= 1) {
    sc += __shfl_xor(sc, off, 32);
    ss += __shfl_xor(ss, off, 32);
  }

  // ---- main correlation: dual stride-1 windows, immediate offsets ----
  const float4* wbase0 = reinterpret_cast<const float4*>(hbase) + (63 - m);
  const float4* wbase1 = reinterpret_cast<const float4*>(hbase) + (31 - m);
  const float4* vbase  = reinterpret_cast<const float4*>(hbase + 392);

  float acc00 = 0.f, acc01 = 0.f, acc02 = 0.f, acc03 = 0.f;
  float acc10 = 0.f, acc11 = 0.f, acc12 = 0.f, acc13 = 0.f;

  float4 wr0 = wbase0[0], wr1 = wbase0[1], wr2;
  float4 ws0 = wbase1[0], ws1 = wbase1[1], ws2;
  float4 wv0 = vbase[0], wv1;

#define CHUNK(c, A0, B0, C0, A1, B1, C1, VA, VB)                               \
  do {                                                                         \
    if ((c) < 31) {                                                            \
      (C0) = wbase0[(c) + 2];                                                  \
      (C1) = wbase1[(c) + 2];                                                  \
      (VB) = vbase[(c) + 1];                                                   \
    }                                                                          \
    acc00 = fmaf((VA).x, (A0).w, acc00); acc00 = fmaf((VA).y, (B0).x, acc00);  \
    acc00 = fmaf((VA).z, (B0).y, acc00); acc00 = fmaf((VA).w, (B0).z, acc00);  \
    acc01 = fmaf((VA).x, (A0).z, acc01); acc01 = fmaf((VA).y, (A0).w, acc01);  \
    acc01 = fmaf((VA).z, (B0).x, acc01); acc01 = fmaf((VA).w, (B0).y, acc01);  \
    acc02 = fmaf((VA).x, (A0).y, acc02); acc02 = fmaf((VA).y, (A0).z, acc02);  \
    acc02 = fmaf((VA).z, (A0).w, acc02); acc02 = fmaf((VA).w, (B0).x, acc02);  \
    acc03 = fmaf((VA).x, (A0).x, acc03); acc03 = fmaf((VA).y, (A0).y, acc03);  \
    acc03 = fmaf((VA).z, (A0).z, acc03); acc03 = fmaf((VA).w, (A0).w, acc03);  \
    acc10 = fmaf((VA).x, (A1).w, acc10); acc10 = fmaf((VA).y, (B1).x, acc10);  \
    acc10 = fmaf((VA).z, (B1).y, acc10); acc10 = fmaf((VA).w, (B1).z, acc10);  \
    acc11 = fmaf((VA).x, (A1).z, acc11); acc11 = fmaf((VA).y, (A1).w, acc11);  \
    acc11 = fmaf((VA).z, (B1).x, acc11); acc11 = fmaf((VA).w, (B1).y, acc11);  \
    acc12 = fmaf((VA).x, (A1).y, acc12); acc12 = fmaf((VA).y, (A1).z, acc12);  \
    acc12 = fmaf((VA).z, (A1).w, acc12); acc12 = fmaf((VA).w, (B1).x, acc12);  \
    acc13 = fmaf((VA).x, (A1).x, acc13); acc13 = fmaf((VA).y, (A1).y, acc13);  \
    acc13 = fmaf((VA).z, (A1).z, acc13); acc13 = fmaf((VA).w, (A1).w, acc13);  \
  } while (0)

  CHUNK( 0, wr0, wr1, wr2, ws0, ws1, ws2, wv0, wv1);
  CHUNK( 1, wr1, wr2, wr0, ws1, ws2, ws0, wv1, wv0);
  CHUNK( 2, wr2, wr0, wr1, ws2, ws0, ws1, wv0, wv1);
  CHUNK( 3, wr0, wr1, wr2, ws0, ws1, ws2, wv1, wv0);
  CHUNK( 4, wr1, wr2, wr0, ws1, ws2, ws0, wv0, wv1);
  CHUNK( 5, wr2, wr0, wr1, ws2, ws0, ws1, wv1, wv0);
  CHUNK( 6, wr0, wr1, wr2, ws0, ws1, ws2, wv0, wv1);
  CHUNK( 7, wr1, wr2, wr0, ws1, ws2, ws0, wv1, wv0);
  CHUNK( 8, wr2, wr0, wr1, ws2, ws0, ws1, wv0, wv1);
  CHUNK( 9, wr0, wr1, wr2, ws0, ws1, ws2, wv1, wv0);
  CHUNK(10, wr1, wr2, wr0, ws1, ws2, ws0, wv0, wv1);
  CHUNK(11, wr2, wr0, wr1, ws2, ws0, ws1, wv1, wv0);
  CHUNK(12, wr0, wr1, wr2, ws0, ws1, ws2, wv0, wv1);
  CHUNK(13, wr1, wr2, wr0, ws1, ws2, ws0, wv1, wv0);
  CHUNK(14, wr2, wr0, wr1, ws2, ws0, ws1, wv0, wv1);
  CHUNK(15, wr0, wr1, wr2, ws0, ws1, ws2, wv1, wv0);
  CHUNK(16, wr1, wr2, wr0, ws1, ws2, ws0, wv0, wv1);
  CHUNK(17, wr2, wr0, wr1, ws2, ws0, ws1, wv1, wv0);
  CHUNK(18, wr0, wr1, wr2, ws0, ws1, ws2, wv0, wv1);
  CHUNK(19, wr1, wr2, wr0, ws1, ws2, ws0, wv1, wv0);
  CHUNK(20, wr2, wr0, wr1, ws2, ws0, ws1, wv0, wv1);
  CHUNK(21, wr0, wr1, wr2, ws0, ws1, ws2, wv1, wv0);
  CHUNK(22, wr1, wr2, wr0, ws1, ws2, ws0, wv0, wv1);
  CHUNK(23, wr2, wr0, wr1, ws2, ws0, ws1, wv1, wv0);
  CHUNK(24, wr0, wr1, wr2, ws0, ws1, ws2, wv0, wv1);
  CHUNK(25, wr1, wr2, wr0, ws1, ws2, ws0, wv1, wv0);
  CHUNK(26, wr2, wr0, wr1, ws2, ws0, ws1, wv0, wv1);
  CHUNK(27, wr0, wr1, wr2, ws0, ws1, ws2, wv1, wv0);
  CHUNK(28, wr1, wr2, wr0, ws1, ws2, ws0, wv0, wv1);
  CHUNK(29, wr2, wr0, wr1, ws2, ws0, ws1, wv1, wv0);
  CHUNK(30, wr0, wr1, wr2, ws0, ws1, ws2, wv0, wv1);
  CHUNK(31, wr1, wr2, wr0, ws1, ws2, ws0, wv1, wv0);
#undef CHUNK

  // ---- per-lane stats: 8 lags, ascending (4m+q then 128+4m+q) ----
  float sum, ssq, mx; int mi;
  mx = acc00; mi = 4 * m;
  sum = acc00; ssq = acc00 * acc00;
  if (acc01 > mx) { mx = acc01; mi = 4 * m + 1; }
  sum += acc01; ssq = fmaf(acc01, acc01, ssq);
  if (acc02 > mx) { mx = acc02; mi = 4 * m + 2; }
  sum += acc02; ssq = fmaf(acc02, acc02, ssq);
  if (acc03 > mx) { mx = acc03; mi = 4 * m + 3; }
  sum += acc03; ssq = fmaf(acc03, acc03, ssq);
  if (acc10 > mx) { mx = acc10; mi = 128 + 4 * m; }
  sum += acc10; ssq = fmaf(acc10, acc10, ssq);
  if (acc11 > mx) { mx = acc11; mi = 128 + 4 * m + 1; }
  sum += acc11; ssq = fmaf(acc11, acc11, ssq);
  if (acc12 > mx) { mx = acc12; mi = 128 + 4 * m + 2; }
  sum += acc12; ssq = fmaf(acc12, acc12, ssq);
  const bool real13 = (m < 31);                 // sh=255 dummy at m=31
  const float c13 = real13 ? acc13 : NEG_BIG;
  if (c13 > mx) { mx = c13; mi = 128 + 4 * m + 3; }
  const float c13s = real13 ? acc13 : 0.f;
  sum += c13s; ssq = fmaf(c13s, c13s, ssq);

  // cross-lane reduce over the 32-lane half (max with min-index tie-break)
#pragma unroll
  for (int off = 1; off < 32; off <<= 1) {
    const float ov = __shfl_xor(mx, off, 32);
    const int   oi = __shfl_xor(mi, off, 32);
    if (ov > mx || (ov == mx && oi < mi)) { mx = ov; mi = oi; }
    sum += __shfl_xor(sum, off, 32);
    ssq += __shfl_xor(ssq, off, 32);
  }

  // ---- fold normalization: corr_normalized = (iv*ia) * corr_raw ----
  const float s = iv * ia;
  const float delay = (float)mi - 127.0f;
  const float rv = nv / fmaxf(nv, 1e-12f);   // ||v_normalized||
  const float ra = na / fmaxf(na, 1e-12f);
  const float cstr = (mx * s) / (rv * ra + 1e-6f);
  const float mean_r = sum * (1.0f / 255.0f);
  const float var_r  = fmaxf(ssq * (1.0f / 255.0f) - mean_r * mean_r, 0.0f);
  const float cstd = s * sqrtf(var_r);
  const float ve = rv * rv, ae = ra * ra;
  const float er = ve / (ae + 1e-6f);
  const float mc = sc * (1.0f / 128.0f), ms = ss * (1.0f / 128.0f);
  const float pc = sqrtf(mc * mc + ms * ms);
  const float cons = 1.0f / (1.0f + fabsf(delay));

  const float s0 = delay * 0.1f;
  const float s1 = cstr;
  const float s2 = cstd;
  const float s3 = er;
  const float s4 = pc;
  const float s5 = cons;

  // ---- MLP: lane m of each half computes output feature m ----
  float h[16];
#pragma unroll
  for (int k = 0; k < 16; ++k) {
    float acch = b1[k];
    acch = fmaf(s0, W1[0 * 16 + k], acch);
    acch = fmaf(s1, W1[1 * 16 + k], acch);
    acch = fmaf(s2, W1[2 * 16 + k], acch);
    acch = fmaf(s3, W1[3 * 16 + k], acch);
    acch = fmaf(s4, W1[4 * 16 + k], acch);
    acch = fmaf(s5, W1[5 * 16 + k], acch);
    h[k] = fmaxf(acch, 0.0f);
  }
  float o = b2[m];
#pragma unroll
  for (int k = 0; k < 16; ++k) o = fmaf(h[k], W2[k * 32 + m], o);
  out[(size_t)b * 32 + m] = o;
}

extern "C" void kernel_launch(void* const* d_in, const int* in_sizes, int n_in,
                              void* d_out, int out_size, void* d_ws, size_t ws_size,
                              hipStream_t stream) {
  const float* video = (const float*)d_in[0];
  const float* audio = (const float*)d_in[1];
  const float* W1 = (const float*)d_in[2];
  const float* b1 = (const float*)d_in[3];
  const float* W2 = (const float*)d_in[4];
  const float* b2 = (const float*)d_in[5];
  float* out = (float*)d_out;

  const int B = in_sizes[0] / 128;        // 65536 samples
  const int blocks = B / 8;               // 2 samples/wave * 4 waves/block
  avsync_kernel<<<blocks, 256, 0, stream>>>(video, audio, W1, b1, W2, b2, out);
}

// Round 5
// 111.899 us; speedup vs baseline: 1.0134x; 1.0134x over previous
//
#include <hip/hip_runtime.h>

#define NEG_BIG (-3.0e38f)

// One block = 256 threads = 4 waves; each wave handles 2 samples (one per
// 32-lane half). Lane m owns TWO 4-lag groups: sh = 4m+q and sh = 128+4m+q
// (q=0..3; sh=255 is a dummy). Each group's sliding window moves at lane
// stride -1 slot (conflict-free linear LDS, compile-time chunk offsets).
// Per-half LDS (544 floats):
//   apad floats [0,392): zeros[0,128) | raw audio [128,256) | zeros [256,392)
//   video floats [392,520)  (broadcast-read per chunk)
// corr_raw[sh] = sum_j v[j]*apad[j - sh + 255]; window slot for group g:
//   S_g(c) = c + 63 - 32*g - m; w[t] = apad[4*S + t]; acc_gq += v[4c+e]*w[3+e-q].
// NOTE: no second launch_bounds arg — R3's (256,8) forced <=64 VGPR and
// spilled the ring registers to scratch (WRITE_SIZE 8.2->57 MB).
__global__ __launch_bounds__(256) void avsync_kernel(
    const float* __restrict__ video, const float* __restrict__ audio,
    const float* __restrict__ W1, const float* __restrict__ b1,
    const float* __restrict__ W2, const float* __restrict__ b2,
    float* __restrict__ out) {
  __shared__ float lds[4][2][544];

  const int tid  = threadIdx.x;
  const int wid  = tid >> 6;
  const int lane = tid & 63;
  const int half = lane >> 5;
  const int m    = lane & 31;
  const int b    = (int)blockIdx.x * 8 + wid * 2 + half;

  float* hbase = &lds[wid][half][0];

  const float4 v4 = *reinterpret_cast<const float4*>(video + (size_t)b * 128 + 4 * m);
  const float4 a4 = *reinterpret_cast<const float4*>(audio + (size_t)b * 128 + 4 * m);

  // ---- stage raw data (wave-private region, no barrier needed) ----
  float4 z4; z4.x = z4.y = z4.z = z4.w = 0.0f;
  float4* sl = reinterpret_cast<float4*>(hbase);
  sl[m]      = z4;        // apad slots [0,32)   = zeros
  sl[64 + m] = z4;        // apad slots [64,96)  = zeros
  if (m < 2) sl[96 + m] = z4;   // slots 96,97 zeros
  sl[32 + m] = a4;        // apad slots [32,64)  = raw audio
  *reinterpret_cast<float4*>(hbase + 392 + 4 * m) = v4;   // video

  // ---- norms (per half) ----
  float pv = v4.x * v4.x + v4.y * v4.y + v4.z * v4.z + v4.w * v4.w;
  float pa = a4.x * a4.x + a4.y * a4.y + a4.z * a4.z + a4.w * a4.w;
#pragma unroll
  for (int off = 1; off < 32; off <<= 1) {
    pv += __shfl_xor(pv, off, 32);
    pa += __shfl_xor(pa, off, 32);
  }
  const float nv = sqrtf(pv);
  const float na = sqrtf(pa);
  const float iv = 1.0f / fmaxf(nv, 1e-12f);
  const float ia = 1.0f / fmaxf(na, 1e-12f);

  // ---- phase statistic on normalized difference ----
  const float d0 = v4.x * iv - a4.x * ia;
  const float d1 = v4.y * iv - a4.y * ia;
  const float d2 = v4.z * iv - a4.z * ia;
  const float d3 = v4.w * iv - a4.w * ia;
  float sc = __cosf(d0) + __cosf(d1) + __cosf(d2) + __cosf(d3);
  float ss = __sinf(d0) + __sinf(d1) + __sinf(d2) + __sinf(d3);
#pragma unroll
  for (int off = 1; off < 32; off <<= 1) {
    sc += __shfl_xor(sc, off, 32);
    ss += __shfl_xor(ss, off, 32);
  }

  // ---- precompute all corr-independent stats (shrinks loop-carried set) ----
  const float s_norm = iv * ia;                       // folds normalization
  const float rv = nv / fmaxf(nv, 1e-12f);            // ||v_normalized||
  const float ra = na / fmaxf(na, 1e-12f);
  const float rvra = rv * ra;
  const float er = (rv * rv) / (ra * ra + 1e-6f);     // energy_ratio
  const float mc = sc * (1.0f / 128.0f), ms = ss * (1.0f / 128.0f);
  const float pc = sqrtf(mc * mc + ms * ms);          // phase_coherence

  // ---- main correlation: dual stride-1 windows, immediate offsets ----
  const float4* wbase0 = reinterpret_cast<const float4*>(hbase) + (63 - m);
  const float4* wbase1 = reinterpret_cast<const float4*>(hbase) + (31 - m);
  const float4* vbase  = reinterpret_cast<const float4*>(hbase + 392);

  float acc00 = 0.f, acc01 = 0.f, acc02 = 0.f, acc03 = 0.f;
  float acc10 = 0.f, acc11 = 0.f, acc12 = 0.f, acc13 = 0.f;

  float4 wr0 = wbase0[0], wr1 = wbase0[1], wr2;
  float4 ws0 = wbase1[0], ws1 = wbase1[1], ws2;
  float4 wv0 = vbase[0], wv1;

#define CHUNK(c, A0, B0, C0, A1, B1, C1, VA, VB)                               \
  do {                                                                         \
    if ((c) < 31) {                                                            \
      (C0) = wbase0[(c) + 2];                                                  \
      (C1) = wbase1[(c) + 2];                                                  \
      (VB) = vbase[(c) + 1];                                                   \
    }                                                                          \
    acc00 = fmaf((VA).x, (A0).w, acc00); acc00 = fmaf((VA).y, (B0).x, acc00);  \
    acc00 = fmaf((VA).z, (B0).y, acc00); acc00 = fmaf((VA).w, (B0).z, acc00);  \
    acc01 = fmaf((VA).x, (A0).z, acc01); acc01 = fmaf((VA).y, (A0).w, acc01);  \
    acc01 = fmaf((VA).z, (B0).x, acc01); acc01 = fmaf((VA).w, (B0).y, acc01);  \
    acc02 = fmaf((VA).x, (A0).y, acc02); acc02 = fmaf((VA).y, (A0).z, acc02);  \
    acc02 = fmaf((VA).z, (A0).w, acc02); acc02 = fmaf((VA).w, (B0).x, acc02);  \
    acc03 = fmaf((VA).x, (A0).x, acc03); acc03 = fmaf((VA).y, (A0).y, acc03);  \
    acc03 = fmaf((VA).z, (A0).z, acc03); acc03 = fmaf((VA).w, (A0).w, acc03);  \
    acc10 = fmaf((VA).x, (A1).w, acc10); acc10 = fmaf((VA).y, (B1).x, acc10);  \
    acc10 = fmaf((VA).z, (B1).y, acc10); acc10 = fmaf((VA).w, (B1).z, acc10);  \
    acc11 = fmaf((VA).x, (A1).z, acc11); acc11 = fmaf((VA).y, (A1).w, acc11);  \
    acc11 = fmaf((VA).z, (B1).x, acc11); acc11 = fmaf((VA).w, (B1).y, acc11);  \
    acc12 = fmaf((VA).x, (A1).y, acc12); acc12 = fmaf((VA).y, (A1).z, acc12);  \
    acc12 = fmaf((VA).z, (A1).w, acc12); acc12 = fmaf((VA).w, (B1).x, acc12);  \
    acc13 = fmaf((VA).x, (A1).x, acc13); acc13 = fmaf((VA).y, (A1).y, acc13);  \
    acc13 = fmaf((VA).z, (A1).z, acc13); acc13 = fmaf((VA).w, (A1).w, acc13);  \
  } while (0)

  CHUNK( 0, wr0, wr1, wr2, ws0, ws1, ws2, wv0, wv1);
  CHUNK( 1, wr1, wr2, wr0, ws1, ws2, ws0, wv1, wv0);
  CHUNK( 2, wr2, wr0, wr1, ws2, ws0, ws1, wv0, wv1);
  CHUNK( 3, wr0, wr1, wr2, ws0, ws1, ws2, wv1, wv0);
  CHUNK( 4, wr1, wr2, wr0, ws1, ws2, ws0, wv0, wv1);
  CHUNK( 5, wr2, wr0, wr1, ws2, ws0, ws1, wv1, wv0);
  CHUNK( 6, wr0, wr1, wr2, ws0, ws1, ws2, wv0, wv1);
  CHUNK( 7, wr1, wr2, wr0, ws1, ws2, ws0, wv1, wv0);
  CHUNK( 8, wr2, wr0, wr1, ws2, ws0, ws1, wv0, wv1);
  CHUNK( 9, wr0, wr1, wr2, ws0, ws1, ws2, wv1, wv0);
  CHUNK(10, wr1, wr2, wr0, ws1, ws2, ws0, wv0, wv1);
  CHUNK(11, wr2, wr0, wr1, ws2, ws0, ws1, wv1, wv0);
  CHUNK(12, wr0, wr1, wr2, ws0, ws1, ws2, wv0, wv1);
  CHUNK(13, wr1, wr2, wr0, ws1, ws2, ws0, wv1, wv0);
  CHUNK(14, wr2, wr0, wr1, ws2, ws0, ws1, wv0, wv1);
  CHUNK(15, wr0, wr1, wr2, ws0, ws1, ws2, wv1, wv0);
  CHUNK(16, wr1, wr2, wr0, ws1, ws2, ws0, wv0, wv1);
  CHUNK(17, wr2, wr0, wr1, ws2, ws0, ws1, wv1, wv0);
  CHUNK(18, wr0, wr1, wr2, ws0, ws1, ws2, wv0, wv1);
  CHUNK(19, wr1, wr2, wr0, ws1, ws2, ws0, wv1, wv0);
  CHUNK(20, wr2, wr0, wr1, ws2, ws0, ws1, wv0, wv1);
  CHUNK(21, wr0, wr1, wr2, ws0, ws1, ws2, wv1, wv0);
  CHUNK(22, wr1, wr2, wr0, ws1, ws2, ws0, wv0, wv1);
  CHUNK(23, wr2, wr0, wr1, ws2, ws0, ws1, wv1, wv0);
  CHUNK(24, wr0, wr1, wr2, ws0, ws1, ws2, wv0, wv1);
  CHUNK(25, wr1, wr2, wr0, ws1, ws2, ws0, wv1, wv0);
  CHUNK(26, wr2, wr0, wr1, ws2, ws0, ws1, wv0, wv1);
  CHUNK(27, wr0, wr1, wr2, ws0, ws1, ws2, wv1, wv0);
  CHUNK(28, wr1, wr2, wr0, ws1, ws2, ws0, wv0, wv1);
  CHUNK(29, wr2, wr0, wr1, ws2, ws0, ws1, wv1, wv0);
  CHUNK(30, wr0, wr1, wr2, ws0, ws1, ws2, wv0, wv1);
  CHUNK(31, wr1, wr2, wr0, ws1, ws2, ws0, wv1, wv0);
#undef CHUNK

  // ---- per-lane stats: 8 lags, ascending (4m+q then 128+4m+q) ----
  float sum, ssq, mx; int mi;
  mx = acc00; mi = 4 * m;
  sum = acc00; ssq = acc00 * acc00;
  if (acc01 > mx) { mx = acc01; mi = 4 * m + 1; }
  sum += acc01; ssq = fmaf(acc01, acc01, ssq);
  if (acc02 > mx) { mx = acc02; mi = 4 * m + 2; }
  sum += acc02; ssq = fmaf(acc02, acc02, ssq);
  if (acc03 > mx) { mx = acc03; mi = 4 * m + 3; }
  sum += acc03; ssq = fmaf(acc03, acc03, ssq);
  if (acc10 > mx) { mx = acc10; mi = 128 + 4 * m; }
  sum += acc10; ssq = fmaf(acc10, acc10, ssq);
  if (acc11 > mx) { mx = acc11; mi = 128 + 4 * m + 1; }
  sum += acc11; ssq = fmaf(acc11, acc11, ssq);
  if (acc12 > mx) { mx = acc12; mi = 128 + 4 * m + 2; }
  sum += acc12; ssq = fmaf(acc12, acc12, ssq);
  const bool real13 = (m < 31);                 // sh=255 dummy at m=31
  const float c13 = real13 ? acc13 : NEG_BIG;
  if (c13 > mx) { mx = c13; mi = 128 + 4 * m + 3; }
  const float c13s = real13 ? acc13 : 0.f;
  sum += c13s; ssq = fmaf(c13s, c13s, ssq);

  // cross-lane reduce over the 32-lane half (max with min-index tie-break)
#pragma unroll
  for (int off = 1; off < 32; off <<= 1) {
    const float ov = __shfl_xor(mx, off, 32);
    const int   oi = __shfl_xor(mi, off, 32);
    if (ov > mx || (ov == mx && oi < mi)) { mx = ov; mi = oi; }
    sum += __shfl_xor(sum, off, 32);
    ssq += __shfl_xor(ssq, off, 32);
  }

  // ---- finalize stats (corr_normalized = s_norm * corr_raw) ----
  const float delay = (float)mi - 127.0f;
  const float cstr = (mx * s_norm) / (rvra + 1e-6f);
  const float mean_r = sum * (1.0f / 255.0f);
  const float var_r  = fmaxf(ssq * (1.0f / 255.0f) - mean_r * mean_r, 0.0f);
  const float cstd = s_norm * sqrtf(var_r);
  const float cons = 1.0f / (1.0f + fabsf(delay));

  const float s0 = delay * 0.1f;
  const float s1 = cstr;
  const float s2 = cstd;
  const float s3 = er;
  const float s4 = pc;
  const float s5 = cons;

  // ---- MLP: lane m of each half computes output feature m ----
  float h[16];
#pragma unroll
  for (int k = 0; k < 16; ++k) {
    float acch = b1[k];
    acch = fmaf(s0, W1[0 * 16 + k], acch);
    acch = fmaf(s1, W1[1 * 16 + k], acch);
    acch = fmaf(s2, W1[2 * 16 + k], acch);
    acch = fmaf(s3, W1[3 * 16 + k], acch);
    acch = fmaf(s4, W1[4 * 16 + k], acch);
    acch = fmaf(s5, W1[5 * 16 + k], acch);
    h[k] = fmaxf(acch, 0.0f);
  }
  float o = b2[m];
#pragma unroll
  for (int k = 0; k < 16; ++k) o = fmaf(h[k], W2[k * 32 + m], o);
  out[(size_t)b * 32 + m] = o;
}

extern "C" void kernel_launch(void* const* d_in, const int* in_sizes, int n_in,
                              void* d_out, int out_size, void* d_ws, size_t ws_size,
                              hipStream_t stream) {
  const float* video = (const float*)d_in[0];
  const float* audio = (const float*)d_in[1];
  const float* W1 = (const float*)d_in[2];
  const float* b1 = (const float*)d_in[3];
  const float* W2 = (const float*)d_in[4];
  const float* b2 = (const float*)d_in[5];
  float* out = (float*)d_out;

  const int B = in_sizes[0] / 128;        // 65536 samples
  const int blocks = B / 8;               // 2 samples/wave * 4 waves/block
  avsync_kernel<<<blocks, 256, 0, stream>>>(video, audio, W1, b1, W2, b2, out);
}

// Round 6
// 73.476 us; speedup vs baseline: 1.5434x; 1.5229x over previous
//
#include <hip/hip_runtime.h>

#define NEG_BIG (-3.0e38f)

// One block = 256 threads = 4 waves; each wave handles 2 samples (one per
// 32-lane half). Lane m owns 8 lags sh = (248-8m)+q, q=0..7 (sh=255 dummy).
// Single sliding window: W[t] = apad[8m+4c+t], t=0..11 (three float4 slots),
// base slot 2m, chunk offset = compile-time immediate. Named-register rings:
// 5-deep window (lead-2 prefetch), 3-deep v (lead-2).
// Per-half region = 528 floats (2112 B == 64 mod 128): the +64B stagger puts
// half 1 on the complementary 4 LDS bank-groups of half 0 for every access,
// so each wave b128 hits all 8 groups x 8 lanes = structural 8-phase minimum.
//   apad slots 0..95: zeros[0,128) | raw audio [128,256) | zeros [256,384)
//   video floats [384,512) (slots 96..127), pad [512,528).
// corr_raw[sh] = sum_j v[j]*apad[j-sh+255]; acc[q] += v[4c+e]*W[7+e-q].
__global__ __launch_bounds__(256) void avsync_kernel(
    const float* __restrict__ video, const float* __restrict__ audio,
    const float* __restrict__ W1, const float* __restrict__ b1,
    const float* __restrict__ W2, const float* __restrict__ b2,
    float* __restrict__ out) {
  __shared__ float lds[4224];   // 4 waves * 2 halves * 528 floats

  const int tid  = threadIdx.x;
  const int wid  = tid >> 6;
  const int lane = tid & 63;
  const int half = lane >> 5;
  const int m    = lane & 31;
  const int b    = (int)blockIdx.x * 8 + wid * 2 + half;

  float* hbase = &lds[(wid * 2 + half) * 528];

  const float4 v4 = *reinterpret_cast<const float4*>(video + (size_t)b * 128 + 4 * m);
  const float4 a4 = *reinterpret_cast<const float4*>(audio + (size_t)b * 128 + 4 * m);

  // ---- stage raw data (wave-private region, no barrier needed) ----
  float4 z4; z4.x = z4.y = z4.z = z4.w = 0.0f;
  float4* sl = reinterpret_cast<float4*>(hbase);
  sl[m]      = z4;        // apad slots [0,32)   = zeros
  sl[64 + m] = z4;        // apad slots [64,96)  = zeros
  sl[32 + m] = a4;        // apad slots [32,64)  = raw audio
  sl[96 + m] = v4;        // video
  // ---- norms (per half) ----
  float pv = v4.x * v4.x + v4.y * v4.y + v4.z * v4.z + v4.w * v4.w;
  float pa = a4.x * a4.x + a4.y * a4.y + a4.z * a4.z + a4.w * a4.w;
#pragma unroll
  for (int off = 1; off < 32; off <<= 1) {
    pv += __shfl_xor(pv, off, 32);
    pa += __shfl_xor(pa, off, 32);
  }
  const float nv = sqrtf(pv);
  const float na = sqrtf(pa);
  const float iv = 1.0f / fmaxf(nv, 1e-12f);
  const float ia = 1.0f / fmaxf(na, 1e-12f);

  // ---- phase statistic on normalized difference ----
  const float d0 = v4.x * iv - a4.x * ia;
  const float d1 = v4.y * iv - a4.y * ia;
  const float d2 = v4.z * iv - a4.z * ia;
  const float d3 = v4.w * iv - a4.w * ia;
  float sc = __cosf(d0) + __cosf(d1) + __cosf(d2) + __cosf(d3);
  float ss = __sinf(d0) + __sinf(d1) + __sinf(d2) + __sinf(d3);
#pragma unroll
  for (int off = 1; off < 32; off <<= 1) {
    sc += __shfl_xor(sc, off, 32);
    ss += __shfl_xor(ss, off, 32);
  }

  // ---- corr-independent stats precompute (small loop-carried set) ----
  const float s_norm = iv * ia;
  const float rv = nv / fmaxf(nv, 1e-12f);
  const float ra = na / fmaxf(na, 1e-12f);
  const float rvra = rv * ra;
  const float er = (rv * rv) / (ra * ra + 1e-6f);
  const float mc = sc * (1.0f / 128.0f), ms = ss * (1.0f / 128.0f);
  const float pc = sqrtf(mc * mc + ms * ms);

  // ---- main correlation: single stride-2 window, immediate offsets ----
  const float4* wbase = reinterpret_cast<const float4*>(hbase) + 2 * m;
  const float4* vbase = reinterpret_cast<const float4*>(hbase) + 96;

  float acc0 = 0.f, acc1 = 0.f, acc2 = 0.f, acc3 = 0.f;
  float acc4 = 0.f, acc5 = 0.f, acc6 = 0.f, acc7 = 0.f;

  float4 P0 = wbase[0], P1 = wbase[1], P2 = wbase[2], P3 = wbase[3], P4;
  float4 Q0 = vbase[0], Q1 = vbase[1], Q2;

  // chunk c: A=P[c%5], B=P[(c+1)%5], C=P[(c+2)%5], read wbase[c+4] -> P[(c+4)%5];
  //          VA=Q[c%3], read vbase[c+2] -> Q[(c+2)%3].  Reads only for c<30.
#define CHUNK(c, A, B, C, D, VA, VQ)                                           \
  do {                                                                         \
    if ((c) < 30) {                                                            \
      (D)  = wbase[(c) + 4];                                                   \
      (VQ) = vbase[(c) + 2];                                                   \
    }                                                                          \
    acc0 = fmaf((VA).x, (B).w, acc0); acc0 = fmaf((VA).y, (C).x, acc0);        \
    acc0 = fmaf((VA).z, (C).y, acc0); acc0 = fmaf((VA).w, (C).z, acc0);        \
    acc1 = fmaf((VA).x, (B).z, acc1); acc1 = fmaf((VA).y, (B).w, acc1);        \
    acc1 = fmaf((VA).z, (C).x, acc1); acc1 = fmaf((VA).w, (C).y, acc1);        \
    acc2 = fmaf((VA).x, (B).y, acc2); acc2 = fmaf((VA).y, (B).z, acc2);        \
    acc2 = fmaf((VA).z, (B).w, acc2); acc2 = fmaf((VA).w, (C).x, acc2);        \
    acc3 = fmaf((VA).x, (B).x, acc3); acc3 = fmaf((VA).y, (B).y, acc3);        \
    acc3 = fmaf((VA).z, (B).z, acc3); acc3 = fmaf((VA).w, (B).w, acc3);        \
    acc4 = fmaf((VA).x, (A).w, acc4); acc4 = fmaf((VA).y, (B).x, acc4);        \
    acc4 = fmaf((VA).z, (B).y, acc4); acc4 = fmaf((VA).w, (B).z, acc4);        \
    acc5 = fmaf((VA).x, (A).z, acc5); acc5 = fmaf((VA).y, (A).w, acc5);        \
    acc5 = fmaf((VA).z, (B).x, acc5); acc5 = fmaf((VA).w, (B).y, acc5);        \
    acc6 = fmaf((VA).x, (A).y, acc6); acc6 = fmaf((VA).y, (A).z, acc6);        \
    acc6 = fmaf((VA).z, (A).w, acc6); acc6 = fmaf((VA).w, (B).x, acc6);        \
    acc7 = fmaf((VA).x, (A).x, acc7); acc7 = fmaf((VA).y, (A).y, acc7);        \
    acc7 = fmaf((VA).z, (A).z, acc7); acc7 = fmaf((VA).w, (A).w, acc7);        \
  } while (0)

  CHUNK( 0, P0, P1, P2, P4, Q0, Q2);
  CHUNK( 1, P1, P2, P3, P0, Q1, Q0);
  CHUNK( 2, P2, P3, P4, P1, Q2, Q1);
  CHUNK( 3, P3, P4, P0, P2, Q0, Q2);
  CHUNK( 4, P4, P0, P1, P3, Q1, Q0);
  CHUNK( 5, P0, P1, P2, P4, Q2, Q1);
  CHUNK( 6, P1, P2, P3, P0, Q0, Q2);
  CHUNK( 7, P2, P3, P4, P1, Q1, Q0);
  CHUNK( 8, P3, P4, P0, P2, Q2, Q1);
  CHUNK( 9, P4, P0, P1, P3, Q0, Q2);
  CHUNK(10, P0, P1, P2, P4, Q1, Q0);
  CHUNK(11, P1, P2, P3, P0, Q2, Q1);
  CHUNK(12, P2, P3, P4, P1, Q0, Q2);
  CHUNK(13, P3, P4, P0, P2, Q1, Q0);
  CHUNK(14, P4, P0, P1, P3, Q2, Q1);
  CHUNK(15, P0, P1, P2, P4, Q0, Q2);
  CHUNK(16, P1, P2, P3, P0, Q1, Q0);
  CHUNK(17, P2, P3, P4, P1, Q2, Q1);
  CHUNK(18, P3, P4, P0, P2, Q0, Q2);
  CHUNK(19, P4, P0, P1, P3, Q1, Q0);
  CHUNK(20, P0, P1, P2, P4, Q2, Q1);
  CHUNK(21, P1, P2, P3, P0, Q0, Q2);
  CHUNK(22, P2, P3, P4, P1, Q1, Q0);
  CHUNK(23, P3, P4, P0, P2, Q2, Q1);
  CHUNK(24, P4, P0, P1, P3, Q0, Q2);
  CHUNK(25, P0, P1, P2, P4, Q1, Q0);
  CHUNK(26, P1, P2, P3, P0, Q2, Q1);
  CHUNK(27, P2, P3, P4, P1, Q0, Q2);
  CHUNK(28, P3, P4, P0, P2, Q1, Q0);
  CHUNK(29, P4, P0, P1, P3, Q2, Q1);
  CHUNK(30, P0, P1, P2, P4, Q0, Q2);
  CHUNK(31, P1, P2, P3, P0, Q1, Q0);
#undef CHUNK

  // ---- per-lane stats: 8 lags, sh = (248-8m)+q ascending in q ----
  const float accv[8] = {acc0, acc1, acc2, acc3, acc4, acc5, acc6, acc7};
  const int sh0 = 248 - 8 * m;
  float sum = 0.f, ssq = 0.f, mx = NEG_BIG;
  int mi = 0;
#pragma unroll
  for (int q = 0; q < 8; ++q) {
    const int sh = sh0 + q;
    const bool realLag = (sh < 255);
    const float cv = accv[q];
    const float cs = realLag ? cv : 0.f;
    sum += cs;
    ssq = fmaf(cs, cs, ssq);
    const float cm = realLag ? cv : NEG_BIG;
    if (cm > mx) { mx = cm; mi = sh; }
  }
  // cross-lane reduce over the 32-lane half (max with min-index tie-break)
#pragma unroll
  for (int off = 1; off < 32; off <<= 1) {
    const float ov = __shfl_xor(mx, off, 32);
    const int   oi = __shfl_xor(mi, off, 32);
    if (ov > mx || (ov == mx && oi < mi)) { mx = ov; mi = oi; }
    sum += __shfl_xor(sum, off, 32);
    ssq += __shfl_xor(ssq, off, 32);
  }

  // ---- finalize stats (corr_normalized = s_norm * corr_raw) ----
  const float delay = (float)mi - 127.0f;
  const float cstr = (mx * s_norm) / (rvra + 1e-6f);
  const float mean_r = sum * (1.0f / 255.0f);
  const float var_r  = fmaxf(ssq * (1.0f / 255.0f) - mean_r * mean_r, 0.0f);
  const float cstd = s_norm * sqrtf(var_r);
  const float cons = 1.0f / (1.0f + fabsf(delay));

  const float s0 = delay * 0.1f;
  const float s1 = cstr;
  const float s2 = cstd;
  const float s3 = er;
  const float s4 = pc;
  const float s5 = cons;

  // ---- MLP: lane m of each half computes output feature m ----
  float h[16];
#pragma unroll
  for (int k = 0; k < 16; ++k) {
    float acch = b1[k];
    acch = fmaf(s0, W1[0 * 16 + k], acch);
    acch = fmaf(s1, W1[1 * 16 + k], acch);
    acch = fmaf(s2, W1[2 * 16 + k], acch);
    acch = fmaf(s3, W1[3 * 16 + k], acch);
    acch = fmaf(s4, W1[4 * 16 + k], acch);
    acch = fmaf(s5, W1[5 * 16 + k], acch);
    h[k] = fmaxf(acch, 0.0f);
  }
  float o = b2[m];
#pragma unroll
  for (int k = 0; k < 16; ++k) o = fmaf(h[k], W2[k * 32 + m], o);
  out[(size_t)b * 32 + m] = o;
}

extern "C" void kernel_launch(void* const* d_in, const int* in_sizes, int n_in,
                              void* d_out, int out_size, void* d_ws, size_t ws_size,
                              hipStream_t stream) {
  const float* video = (const float*)d_in[0];
  const float* audio = (const float*)d_in[1];
  const float* W1 = (const float*)d_in[2];
  const float* b1 = (const float*)d_in[3];
  const float* W2 = (const float*)d_in[4];
  const float* b2 = (const float*)d_in[5];
  float* out = (float*)d_out;

  const int B = in_sizes[0] / 128;        // 65536 samples
  const int blocks = B / 8;               // 2 samples/wave * 4 waves/block
  avsync_kernel<<<blocks, 256, 0, stream>>>(video, audio, W1, b1, W2, b2, out);
}

// Round 9
// 71.978 us; speedup vs baseline: 1.5755x; 1.0208x over previous
//
#include <hip/hip_runtime.h>

#define NEG_BIG (-3.0e38f)

// REVERT to the Round-6 passing kernel (73.5us) with one safe change:
// 512-thread blocks (8 waves) instead of 256 — same per-lane math bit-for-bit,
// half the blocks, LDS 33.8KB/block -> 4 blocks/CU -> full 32 waves/CU ceiling.
//
// One block = 8 waves; each wave handles 2 samples (one per 32-lane half).
// Lane m owns 8 lags sh = (248-8m)+q, q=0..7 (sh=255 dummy).
// Single sliding window: W[t] = apad[8m+4c+t], t=0..11 (three float4 slots),
// base slot 2m, chunk offset = compile-time immediate. Named-register rings:
// 5-deep window (lead-2 prefetch), 3-deep v (lead-2).
// Per-half region = 528 floats (2112 B == 64 mod 128): the +64B stagger puts
// half 1 on the complementary 4 LDS bank-groups of half 0 for every access,
// so each wave b128 hits all 8 groups x 8 lanes = structural 8-phase minimum.
//   apad slots 0..95: zeros[0,128) | raw audio [128,256) | zeros [256,384)
//   video floats [384,512) (slots 96..127), pad [512,528).
// corr_raw[sh] = sum_j v[j]*apad[j-sh+255]; acc[q] += v[4c+e]*W[7+e-q].
__global__ __launch_bounds__(512) void avsync_kernel(
    const float* __restrict__ video, const float* __restrict__ audio,
    const float* __restrict__ W1, const float* __restrict__ b1,
    const float* __restrict__ W2, const float* __restrict__ b2,
    float* __restrict__ out) {
  __shared__ float lds[8448];   // 8 waves * 2 halves * 528 floats

  const int tid  = threadIdx.x;
  const int wid  = tid >> 6;
  const int lane = tid & 63;
  const int half = lane >> 5;
  const int m    = lane & 31;
  const int b    = (int)blockIdx.x * 16 + wid * 2 + half;

  float* hbase = &lds[(wid * 2 + half) * 528];

  const float4 v4 = *reinterpret_cast<const float4*>(video + (size_t)b * 128 + 4 * m);
  const float4 a4 = *reinterpret_cast<const float4*>(audio + (size_t)b * 128 + 4 * m);

  // ---- stage raw data (wave-private region, no barrier needed) ----
  float4 z4; z4.x = z4.y = z4.z = z4.w = 0.0f;
  float4* sl = reinterpret_cast<float4*>(hbase);
  sl[m]      = z4;        // apad slots [0,32)   = zeros
  sl[64 + m] = z4;        // apad slots [64,96)  = zeros
  sl[32 + m] = a4;        // apad slots [32,64)  = raw audio
  sl[96 + m] = v4;        // video
  // ---- norms (per half) ----
  float pv = v4.x * v4.x + v4.y * v4.y + v4.z * v4.z + v4.w * v4.w;
  float pa = a4.x * a4.x + a4.y * a4.y + a4.z * a4.z + a4.w * a4.w;
#pragma unroll
  for (int off = 1; off < 32; off <<= 1) {
    pv += __shfl_xor(pv, off, 32);
    pa += __shfl_xor(pa, off, 32);
  }
  const float nv = sqrtf(pv);
  const float na = sqrtf(pa);
  const float iv = 1.0f / fmaxf(nv, 1e-12f);
  const float ia = 1.0f / fmaxf(na, 1e-12f);

  // ---- phase statistic on normalized difference ----
  const float d0 = v4.x * iv - a4.x * ia;
  const float d1 = v4.y * iv - a4.y * ia;
  const float d2 = v4.z * iv - a4.z * ia;
  const float d3 = v4.w * iv - a4.w * ia;
  float sc = __cosf(d0) + __cosf(d1) + __cosf(d2) + __cosf(d3);
  float ss = __sinf(d0) + __sinf(d1) + __sinf(d2) + __sinf(d3);
#pragma unroll
  for (int off = 1; off < 32; off <<= 1) {
    sc += __shfl_xor(sc, off, 32);
    ss += __shfl_xor(ss, off, 32);
  }

  // ---- corr-independent stats precompute (small loop-carried set) ----
  const float s_norm = iv * ia;
  const float rv = nv / fmaxf(nv, 1e-12f);
  const float ra = na / fmaxf(na, 1e-12f);
  const float rvra = rv * ra;
  const float er = (rv * rv) / (ra * ra + 1e-6f);
  const float mc = sc * (1.0f / 128.0f), ms = ss * (1.0f / 128.0f);
  const float pc = sqrtf(mc * mc + ms * ms);

  // ---- main correlation: single stride-2 window, immediate offsets ----
  const float4* wbase = reinterpret_cast<const float4*>(hbase) + 2 * m;
  const float4* vbase = reinterpret_cast<const float4*>(hbase) + 96;

  float acc0 = 0.f, acc1 = 0.f, acc2 = 0.f, acc3 = 0.f;
  float acc4 = 0.f, acc5 = 0.f, acc6 = 0.f, acc7 = 0.f;

  float4 P0 = wbase[0], P1 = wbase[1], P2 = wbase[2], P3 = wbase[3], P4;
  float4 Q0 = vbase[0], Q1 = vbase[1], Q2;

  // chunk c: A=P[c%5], B=P[(c+1)%5], C=P[(c+2)%5], read wbase[c+4] -> P[(c+4)%5];
  //          VA=Q[c%3], read vbase[c+2] -> Q[(c+2)%3].  Reads only for c<30.
#define CHUNK(c, A, B, C, D, VA, VQ)                                           \
  do {                                                                         \
    if ((c) < 30) {                                                            \
      (D)  = wbase[(c) + 4];                                                   \
      (VQ) = vbase[(c) + 2];                                                   \
    }                                                                          \
    acc0 = fmaf((VA).x, (B).w, acc0); acc0 = fmaf((VA).y, (C).x, acc0);        \
    acc0 = fmaf((VA).z, (C).y, acc0); acc0 = fmaf((VA).w, (C).z, acc0);        \
    acc1 = fmaf((VA).x, (B).z, acc1); acc1 = fmaf((VA).y, (B).w, acc1);        \
    acc1 = fmaf((VA).z, (C).x, acc1); acc1 = fmaf((VA).w, (C).y, acc1);        \
    acc2 = fmaf((VA).x, (B).y, acc2); acc2 = fmaf((VA).y, (B).z, acc2);        \
    acc2 = fmaf((VA).z, (B).w, acc2); acc2 = fmaf((VA).w, (C).x, acc2);        \
    acc3 = fmaf((VA).x, (B).x, acc3); acc3 = fmaf((VA).y, (B).y, acc3);        \
    acc3 = fmaf((VA).z, (B).z, acc3); acc3 = fmaf((VA).w, (B).w, acc3);        \
    acc4 = fmaf((VA).x, (A).w, acc4); acc4 = fmaf((VA).y, (B).x, acc4);        \
    acc4 = fmaf((VA).z, (B).y, acc4); acc4 = fmaf((VA).w, (B).z, acc4);        \
    acc5 = fmaf((VA).x, (A).z, acc5); acc5 = fmaf((VA).y, (A).w, acc5);        \
    acc5 = fmaf((VA).z, (B).x, acc5); acc5 = fmaf((VA).w, (B).y, acc5);        \
    acc6 = fmaf((VA).x, (A).y, acc6); acc6 = fmaf((VA).y, (A).z, acc6);        \
    acc6 = fmaf((VA).z, (A).w, acc6); acc6 = fmaf((VA).w, (B).x, acc6);        \
    acc7 = fmaf((VA).x, (A).x, acc7); acc7 = fmaf((VA).y, (A).y, acc7);        \
    acc7 = fmaf((VA).z, (A).z, acc7); acc7 = fmaf((VA).w, (A).w, acc7);        \
  } while (0)

  CHUNK( 0, P0, P1, P2, P4, Q0, Q2);
  CHUNK( 1, P1, P2, P3, P0, Q1, Q0);
  CHUNK( 2, P2, P3, P4, P1, Q2, Q1);
  CHUNK( 3, P3, P4, P0, P2, Q0, Q2);
  CHUNK( 4, P4, P0, P1, P3, Q1, Q0);
  CHUNK( 5, P0, P1, P2, P4, Q2, Q1);
  CHUNK( 6, P1, P2, P3, P0, Q0, Q2);
  CHUNK( 7, P2, P3, P4, P1, Q1, Q0);
  CHUNK( 8, P3, P4, P0, P2, Q2, Q1);
  CHUNK( 9, P4, P0, P1, P3, Q0, Q2);
  CHUNK(10, P0, P1, P2, P4, Q1, Q0);
  CHUNK(11, P1, P2, P3, P0, Q2, Q1);
  CHUNK(12, P2, P3, P4, P1, Q0, Q2);
  CHUNK(13, P3, P4, P0, P2, Q1, Q0);
  CHUNK(14, P4, P0, P1, P3, Q2, Q1);
  CHUNK(15, P0, P1, P2, P4, Q0, Q2);
  CHUNK(16, P1, P2, P3, P0, Q1, Q0);
  CHUNK(17, P2, P3, P4, P1, Q2, Q1);
  CHUNK(18, P3, P4, P0, P2, Q0, Q2);
  CHUNK(19, P4, P0, P1, P3, Q1, Q0);
  CHUNK(20, P0, P1, P2, P4, Q2, Q1);
  CHUNK(21, P1, P2, P3, P0, Q0, Q2);
  CHUNK(22, P2, P3, P4, P1, Q1, Q0);
  CHUNK(23, P3, P4, P0, P2, Q2, Q1);
  CHUNK(24, P4, P0, P1, P3, Q0, Q2);
  CHUNK(25, P0, P1, P2, P4, Q1, Q0);
  CHUNK(26, P1, P2, P3, P0, Q2, Q1);
  CHUNK(27, P2, P3, P4, P1, Q0, Q2);
  CHUNK(28, P3, P4, P0, P2, Q1, Q0);
  CHUNK(29, P4, P0, P1, P3, Q2, Q1);
  CHUNK(30, P0, P1, P2, P4, Q0, Q2);
  CHUNK(31, P1, P2, P3, P0, Q1, Q0);
#undef CHUNK

  // ---- per-lane stats: 8 lags, sh = (248-8m)+q ascending in q ----
  const float accv[8] = {acc0, acc1, acc2, acc3, acc4, acc5, acc6, acc7};
  const int sh0 = 248 - 8 * m;
  float sum = 0.f, ssq = 0.f, mx = NEG_BIG;
  int mi = 0;
#pragma unroll
  for (int q = 0; q < 8; ++q) {
    const int sh = sh0 + q;
    const bool realLag = (sh < 255);
    const float cv = accv[q];
    const float cs = realLag ? cv : 0.f;
    sum += cs;
    ssq = fmaf(cs, cs, ssq);
    const float cm = realLag ? cv : NEG_BIG;
    if (cm > mx) { mx = cm; mi = sh; }
  }
  // cross-lane reduce over the 32-lane half (max with min-index tie-break)
#pragma unroll
  for (int off = 1; off < 32; off <<= 1) {
    const float ov = __shfl_xor(mx, off, 32);
    const int   oi = __shfl_xor(mi, off, 32);
    if (ov > mx || (ov == mx && oi < mi)) { mx = ov; mi = oi; }
    sum += __shfl_xor(sum, off, 32);
    ssq += __shfl_xor(ssq, off, 32);
  }

  // ---- finalize stats (corr_normalized = s_norm * corr_raw) ----
  const float delay = (float)mi - 127.0f;
  const float cstr = (mx * s_norm) / (rvra + 1e-6f);
  const float mean_r = sum * (1.0f / 255.0f);
  const float var_r  = fmaxf(ssq * (1.0f / 255.0f) - mean_r * mean_r, 0.0f);
  const float cstd = s_norm * sqrtf(var_r);
  const float cons = 1.0f / (1.0f + fabsf(delay));

  const float s0 = delay * 0.1f;
  const float s1 = cstr;
  const float s2 = cstd;
  const float s3 = er;
  const float s4 = pc;
  const float s5 = cons;

  // ---- MLP: lane m of each half computes output feature m ----
  float h[16];
#pragma unroll
  for (int k = 0; k < 16; ++k) {
    float acch = b1[k];
    acch = fmaf(s0, W1[0 * 16 + k], acch);
    acch = fmaf(s1, W1[1 * 16 + k], acch);
    acch = fmaf(s2, W1[2 * 16 + k], acch);
    acch = fmaf(s3, W1[3 * 16 + k], acch);
    acch = fmaf(s4, W1[4 * 16 + k], acch);
    acch = fmaf(s5, W1[5 * 16 + k], acch);
    h[k] = fmaxf(acch, 0.0f);
  }
  float o = b2[m];
#pragma unroll
  for (int k = 0; k < 16; ++k) o = fmaf(h[k], W2[k * 32 + m], o);
  out[(size_t)b * 32 + m] = o;
}

extern "C" void kernel_launch(void* const* d_in, const int* in_sizes, int n_in,
                              void* d_out, int out_size, void* d_ws, size_t ws_size,
                              hipStream_t stream) {
  const float* video = (const float*)d_in[0];
  const float* audio = (const float*)d_in[1];
  const float* W1 = (const float*)d_in[2];
  const float* b1 = (const float*)d_in[3];
  const float* W2 = (const float*)d_in[4];
  const float* b2 = (const float*)d_in[5];
  float* out = (float*)d_out;

  const int B = in_sizes[0] / 128;        // 65536 samples
  const int blocks = B / 16;              // 2 samples/wave * 8 waves/block
  avsync_kernel<<<blocks, 512, 0, stream>>>(video, audio, W1, b1, W2, b2, out);
}

// Round 10
// 71.654 us; speedup vs baseline: 1.5826x; 1.0045x over previous
//
#include <hip/hip_runtime.h>

#define NEG_BIG (-3.0e38f)

// R9 kernel (72.0us, passing) with ONE change: deeper LDS prefetch rings.
// Window ring P: 5-deep(lead-2) -> 7-deep(lead-4); video ring Q: 3-deep(lead-2)
// -> 6-deep(lead-5). Same addresses, same fmaf order bit-for-bit; only the
// ds_read issue distance grows (~256-320 cyc ahead of use) so the per-chunk
// lgkmcnt wait is satisfied even under multi-wave LDS queueing.
//
// One block = 8 waves (512 thr); each wave handles 2 samples (one per 32-lane
// half). Lane m owns 8 lags sh = (248-8m)+q, q=0..7 (sh=255 dummy).
// Window W[t] = apad[8m+4c+t], t=0..11 (slots 2m+c .. 2m+c+2).
// Per-half region = 528 floats (2112 B == 64 mod 128 -> halves land on
// complementary bank-groups; structural 8-phase minimum per wave b128).
//   apad slots 0..95: zeros[0,128) | raw audio [128,256) | zeros [256,384)
//   video floats [384,512) (slots 96..127), pad [512,528).
// corr_raw[sh] = sum_j v[j]*apad[j-sh+255]; acc[q] += v[4c+e]*W[7+e-q].
__global__ __launch_bounds__(512) void avsync_kernel(
    const float* __restrict__ video, const float* __restrict__ audio,
    const float* __restrict__ W1, const float* __restrict__ b1,
    const float* __restrict__ W2, const float* __restrict__ b2,
    float* __restrict__ out) {
  __shared__ float lds[8448];   // 8 waves * 2 halves * 528 floats

  const int tid  = threadIdx.x;
  const int wid  = tid >> 6;
  const int lane = tid & 63;
  const int half = lane >> 5;
  const int m    = lane & 31;
  const int b    = (int)blockIdx.x * 16 + wid * 2 + half;

  float* hbase = &lds[(wid * 2 + half) * 528];

  const float4 v4 = *reinterpret_cast<const float4*>(video + (size_t)b * 128 + 4 * m);
  const float4 a4 = *reinterpret_cast<const float4*>(audio + (size_t)b * 128 + 4 * m);

  // ---- stage raw data (wave-private region, no barrier needed) ----
  float4 z4; z4.x = z4.y = z4.z = z4.w = 0.0f;
  float4* sl = reinterpret_cast<float4*>(hbase);
  sl[m]      = z4;        // apad slots [0,32)   = zeros
  sl[64 + m] = z4;        // apad slots [64,96)  = zeros
  sl[32 + m] = a4;        // apad slots [32,64)  = raw audio
  sl[96 + m] = v4;        // video
  // ---- norms (per half) ----
  float pv = v4.x * v4.x + v4.y * v4.y + v4.z * v4.z + v4.w * v4.w;
  float pa = a4.x * a4.x + a4.y * a4.y + a4.z * a4.z + a4.w * a4.w;
#pragma unroll
  for (int off = 1; off < 32; off <<= 1) {
    pv += __shfl_xor(pv, off, 32);
    pa += __shfl_xor(pa, off, 32);
  }
  const float nv = sqrtf(pv);
  const float na = sqrtf(pa);
  const float iv = 1.0f / fmaxf(nv, 1e-12f);
  const float ia = 1.0f / fmaxf(na, 1e-12f);

  // ---- phase statistic on normalized difference ----
  const float d0 = v4.x * iv - a4.x * ia;
  const float d1 = v4.y * iv - a4.y * ia;
  const float d2 = v4.z * iv - a4.z * ia;
  const float d3 = v4.w * iv - a4.w * ia;
  float sc = __cosf(d0) + __cosf(d1) + __cosf(d2) + __cosf(d3);
  float ss = __sinf(d0) + __sinf(d1) + __sinf(d2) + __sinf(d3);
#pragma unroll
  for (int off = 1; off < 32; off <<= 1) {
    sc += __shfl_xor(sc, off, 32);
    ss += __shfl_xor(ss, off, 32);
  }

  // ---- corr-independent stats precompute ----
  const float s_norm = iv * ia;
  const float rv = nv / fmaxf(nv, 1e-12f);
  const float ra = na / fmaxf(na, 1e-12f);
  const float rvra = rv * ra;
  const float er = (rv * rv) / (ra * ra + 1e-6f);
  const float mc = sc * (1.0f / 128.0f), ms = ss * (1.0f / 128.0f);
  const float pc = sqrtf(mc * mc + ms * ms);

  // ---- main correlation: single stride-2 window, immediate offsets ----
  const float4* wbase = reinterpret_cast<const float4*>(hbase) + 2 * m;
  const float4* vbase = reinterpret_cast<const float4*>(hbase) + 96;

  float acc0 = 0.f, acc1 = 0.f, acc2 = 0.f, acc3 = 0.f;
  float acc4 = 0.f, acc5 = 0.f, acc6 = 0.f, acc7 = 0.f;

  // P ring: 7-deep, P[s%7] holds window slot s; prefetch slot c+6 at chunk c.
  float4 P0 = wbase[0], P1 = wbase[1], P2 = wbase[2], P3 = wbase[3],
         P4 = wbase[4], P5 = wbase[5], P6;
  // Q ring: 6-deep, Q[s%6] holds video slot s; prefetch slot c+5 at chunk c.
  float4 Q0 = vbase[0], Q1 = vbase[1], Q2 = vbase[2], Q3 = vbase[3],
         Q4 = vbase[4], Q5;

  // chunk c: A=P[c%7], B=P[(c+1)%7], C=P[(c+2)%7], D=P[(c+6)%7] (prefetch tgt);
  //          VA=Q[c%6], VQ=Q[(c+5)%6] (prefetch tgt).
#define CHUNK(c, A, B, C, D, VA, VQ)                                           \
  do {                                                                         \
    if ((c) <= 27) (D)  = wbase[(c) + 6];                                      \
    if ((c) <= 26) (VQ) = vbase[(c) + 5];                                      \
    acc0 = fmaf((VA).x, (B).w, acc0); acc0 = fmaf((VA).y, (C).x, acc0);        \
    acc0 = fmaf((VA).z, (C).y, acc0); acc0 = fmaf((VA).w, (C).z, acc0);        \
    acc1 = fmaf((VA).x, (B).z, acc1); acc1 = fmaf((VA).y, (B).w, acc1);        \
    acc1 = fmaf((VA).z, (C).x, acc1); acc1 = fmaf((VA).w, (C).y, acc1);        \
    acc2 = fmaf((VA).x, (B).y, acc2); acc2 = fmaf((VA).y, (B).z, acc2);        \
    acc2 = fmaf((VA).z, (B).w, acc2); acc2 = fmaf((VA).w, (C).x, acc2);        \
    acc3 = fmaf((VA).x, (B).x, acc3); acc3 = fmaf((VA).y, (B).y, acc3);        \
    acc3 = fmaf((VA).z, (B).z, acc3); acc3 = fmaf((VA).w, (B).w, acc3);        \
    acc4 = fmaf((VA).x, (A).w, acc4); acc4 = fmaf((VA).y, (B).x, acc4);        \
    acc4 = fmaf((VA).z, (B).y, acc4); acc4 = fmaf((VA).w, (B).z, acc4);        \
    acc5 = fmaf((VA).x, (A).z, acc5); acc5 = fmaf((VA).y, (A).w, acc5);        \
    acc5 = fmaf((VA).z, (B).x, acc5); acc5 = fmaf((VA).w, (B).y, acc5);        \
    acc6 = fmaf((VA).x, (A).y, acc6); acc6 = fmaf((VA).y, (A).z, acc6);        \
    acc6 = fmaf((VA).z, (A).w, acc6); acc6 = fmaf((VA).w, (B).x, acc6);        \
    acc7 = fmaf((VA).x, (A).x, acc7); acc7 = fmaf((VA).y, (A).y, acc7);        \
    acc7 = fmaf((VA).z, (A).z, acc7); acc7 = fmaf((VA).w, (A).w, acc7);        \
  } while (0)

  CHUNK( 0, P0, P1, P2, P6, Q0, Q5);
  CHUNK( 1, P1, P2, P3, P0, Q1, Q0);
  CHUNK( 2, P2, P3, P4, P1, Q2, Q1);
  CHUNK( 3, P3, P4, P5, P2, Q3, Q2);
  CHUNK( 4, P4, P5, P6, P3, Q4, Q3);
  CHUNK( 5, P5, P6, P0, P4, Q5, Q4);
  CHUNK( 6, P6, P0, P1, P5, Q0, Q5);
  CHUNK( 7, P0, P1, P2, P6, Q1, Q0);
  CHUNK( 8, P1, P2, P3, P0, Q2, Q1);
  CHUNK( 9, P2, P3, P4, P1, Q3, Q2);
  CHUNK(10, P3, P4, P5, P2, Q4, Q3);
  CHUNK(11, P4, P5, P6, P3, Q5, Q4);
  CHUNK(12, P5, P6, P0, P4, Q0, Q5);
  CHUNK(13, P6, P0, P1, P5, Q1, Q0);
  CHUNK(14, P0, P1, P2, P6, Q2, Q1);
  CHUNK(15, P1, P2, P3, P0, Q3, Q2);
  CHUNK(16, P2, P3, P4, P1, Q4, Q3);
  CHUNK(17, P3, P4, P5, P2, Q5, Q4);
  CHUNK(18, P4, P5, P6, P3, Q0, Q5);
  CHUNK(19, P5, P6, P0, P4, Q1, Q0);
  CHUNK(20, P6, P0, P1, P5, Q2, Q1);
  CHUNK(21, P0, P1, P2, P6, Q3, Q2);
  CHUNK(22, P1, P2, P3, P0, Q4, Q3);
  CHUNK(23, P2, P3, P4, P1, Q5, Q4);
  CHUNK(24, P3, P4, P5, P2, Q0, Q5);
  CHUNK(25, P4, P5, P6, P3, Q1, Q0);
  CHUNK(26, P5, P6, P0, P4, Q2, Q1);
  CHUNK(27, P6, P0, P1, P5, Q3, Q2);
  CHUNK(28, P0, P1, P2, P6, Q4, Q3);
  CHUNK(29, P1, P2, P3, P0, Q5, Q4);
  CHUNK(30, P2, P3, P4, P1, Q0, Q5);
  CHUNK(31, P3, P4, P5, P2, Q1, Q0);
#undef CHUNK

  // ---- per-lane stats: 8 lags, sh = (248-8m)+q ascending in q ----
  const float accv[8] = {acc0, acc1, acc2, acc3, acc4, acc5, acc6, acc7};
  const int sh0 = 248 - 8 * m;
  float sum = 0.f, ssq = 0.f, mx = NEG_BIG;
  int mi = 0;
#pragma unroll
  for (int q = 0; q < 8; ++q) {
    const int sh = sh0 + q;
    const bool realLag = (sh < 255);
    const float cv = accv[q];
    const float cs = realLag ? cv : 0.f;
    sum += cs;
    ssq = fmaf(cs, cs, ssq);
    const float cm = realLag ? cv : NEG_BIG;
    if (cm > mx) { mx = cm; mi = sh; }
  }
  // cross-lane reduce over the 32-lane half (max with min-index tie-break)
#pragma unroll
  for (int off = 1; off < 32; off <<= 1) {
    const float ov = __shfl_xor(mx, off, 32);
    const int   oi = __shfl_xor(mi, off, 32);
    if (ov > mx || (ov == mx && oi < mi)) { mx = ov; mi = oi; }
    sum += __shfl_xor(sum, off, 32);
    ssq += __shfl_xor(ssq, off, 32);
  }

  // ---- finalize stats (corr_normalized = s_norm * corr_raw) ----
  const float delay = (float)mi - 127.0f;
  const float cstr = (mx * s_norm) / (rvra + 1e-6f);
  const float mean_r = sum * (1.0f / 255.0f);
  const float var_r  = fmaxf(ssq * (1.0f / 255.0f) - mean_r * mean_r, 0.0f);
  const float cstd = s_norm * sqrtf(var_r);
  const float cons = 1.0f / (1.0f + fabsf(delay));

  const float s0 = delay * 0.1f;
  const float s1 = cstr;
  const float s2 = cstd;
  const float s3 = er;
  const float s4 = pc;
  const float s5 = cons;

  // ---- MLP: lane m of each half computes output feature m ----
  float h[16];
#pragma unroll
  for (int k = 0; k < 16; ++k) {
    float acch = b1[k];
    acch = fmaf(s0, W1[0 * 16 + k], acch);
    acch = fmaf(s1, W1[1 * 16 + k], acch);
    acch = fmaf(s2, W1[2 * 16 + k], acch);
    acch = fmaf(s3, W1[3 * 16 + k], acch);
    acch = fmaf(s4, W1[4 * 16 + k], acch);
    acch = fmaf(s5, W1[5 * 16 + k], acch);
    h[k] = fmaxf(acch, 0.0f);
  }
  float o = b2[m];
#pragma unroll
  for (int k = 0; k < 16; ++k) o = fmaf(h[k], W2[k * 32 + m], o);
  out[(size_t)b * 32 + m] = o;
}

extern "C" void kernel_launch(void* const* d_in, const int* in_sizes, int n_in,
                              void* d_out, int out_size, void* d_ws, size_t ws_size,
                              hipStream_t stream) {
  const float* video = (const float*)d_in[0];
  const float* audio = (const float*)d_in[1];
  const float* W1 = (const float*)d_in[2];
  const float* b1 = (const float*)d_in[3];
  const float* W2 = (const float*)d_in[4];
  const float* b2 = (const float*)d_in[5];
  float* out = (float*)d_out;

  const int B = in_sizes[0] / 128;        // 65536 samples
  const int blocks = B / 16;              // 2 samples/wave * 8 waves/block
  avsync_kernel<<<blocks, 512, 0, stream>>>(video, audio, W1, b1, W2, b2, out);
}